// Round 8
// baseline (849.154 us; speedup 1.0000x reference)
//
#include <hip/hip_runtime.h>
#include <math.h>

using u16 = unsigned short;
typedef __attribute__((ext_vector_type(8))) short short8;
typedef __attribute__((ext_vector_type(4))) float f32x4;

__device__ __forceinline__ float b2f(u16 u) {
    union { unsigned int i; float f; } v; v.i = ((unsigned int)u) << 16; return v.f;
}
__device__ __forceinline__ u16 f2b(float f) {
    union { float f; unsigned int i; } v; v.f = f;
    unsigned int x = v.i;
    return (u16)((x + 0x7FFFu + ((x >> 16) & 1u)) >> 16);
}
// dtype-adaptive external load: fl=1 -> f32, fl=0 -> bf16
__device__ __forceinline__ float ldx(const void* p, long long i, int fl) {
    return fl ? ((const float*)p)[i] : b2f(((const u16*)p)[i]);
}

// ---------------------------------------------------------------------------
// Detect input dtype: read first 4096 u16 of f1 as bf16. flag=1 means f32.
__global__ __launch_bounds__(256) void k_detect(const void* p, int* flag) {
    __shared__ float m[256];
    int t = threadIdx.x;
    const u16* q = (const u16*)p;
    float lm = 0.f;
    for (int j = 0; j < 16; ++j) {
        float v = b2f(q[t * 16 + j]);
        float a = fabsf(v);
        if (!(a <= 1e30f)) a = 1e31f;   // NaN/Inf -> huge
        lm = fmaxf(lm, a);
    }
    m[t] = lm;
    __syncthreads();
    if (t == 0) {
        float mm = 0.f;
        for (int i = 0; i < 256; ++i) mm = fmaxf(mm, m[i]);
        *flag = (mm > 1000.f) ? 1 : 0;
    }
}

// ---------------------------------------------------------------------------
// Weight transpose: conv w (OC=256, IC=256, 3, 3) -> wTo[9][OC][IC] bf16
__global__ __launch_bounds__(256) void k_wt(const void* __restrict__ w,
                                            u16* __restrict__ wTo,
                                            const int* __restrict__ flag) {
    int fl = *flag;
    int idx = blockIdx.x * 256 + threadIdx.x;
    int k  = idx >> 16;          // 0..8
    int oc = (idx >> 8) & 255;
    int ic = idx & 255;
    long long s = (oc * 256 + ic) * 9 + k;
    wTo[idx] = fl ? f2b(((const float*)w)[s]) : ((const u16*)w)[s];
}

// ---------------------------------------------------------------------------
// proj_w transpose: (L=4, C=768, F=256) -> pwT[l][f][c] bf16
__global__ __launch_bounds__(256) void k_pwt(const void* __restrict__ w,
                                             u16* __restrict__ pwT,
                                             const int* __restrict__ flag) {
    int fl = *flag;
    int idx = blockIdx.x * 256 + threadIdx.x;   // 786432 total
    int c = idx % 768;
    int f = (idx / 768) & 255;
    int l = idx / (768 * 256);
    long long s = ((long long)l * 768 + c) * 256 + f;
    pwT[idx] = fl ? f2b(((const float*)w)[s]) : ((const u16*)w)[s];
}

// ---------------------------------------------------------------------------
// Shared MFMA-stage helpers (LDS rows of 72 u16 = 144 B, 16B-aligned chunks)
__device__ __forceinline__ void st_stage(u16 (*As)[72], u16 (*Bs)[72],
                                         int spx, int sq,
                                         const u16* a, const uint4* bq) {
    uint4* da = (uint4*)&As[spx][sq * 32];
    da[0] = ((const uint4*)a)[0]; da[1] = ((const uint4*)a)[1];
    da[2] = ((const uint4*)a)[2]; da[3] = ((const uint4*)a)[3];
    uint4* db = (uint4*)&Bs[spx][sq * 32];
    db[0] = bq[0]; db[1] = bq[1]; db[2] = bq[2]; db[3] = bq[3];
}

__device__ __forceinline__ void frag_mfma(const u16 (*As)[72], const u16 (*Bs)[72],
                                          int mbase, int nbase, int l15, int quad,
                                          f32x4 acc[4][4]) {
    #pragma unroll
    for (int h = 0; h < 2; ++h) {
        short8 af[4], bf[4];
        #pragma unroll
        for (int i = 0; i < 4; ++i)
            af[i] = *(const short8*)&As[mbase + (i << 4) + l15][(h << 5) + (quad << 3)];
        #pragma unroll
        for (int j = 0; j < 4; ++j)
            bf[j] = *(const short8*)&Bs[nbase + (j << 4) + l15][(h << 5) + (quad << 3)];
        #pragma unroll
        for (int i = 0; i < 4; ++i)
            #pragma unroll
            for (int j = 0; j < 4; ++j)
                acc[i][j] = __builtin_amdgcn_mfma_f32_16x16x32_bf16(
                    af[i], bf[j], acc[i][j], 0, 0, 0);
    }
}

// ---------------------------------------------------------------------------
// Fusion pass 1 (MFMA, pipelined BK=64): per (b,l) 128px x 128f GEMM over K=768,
// epilogue gelu * softmax(lw)[l] -> gbuf[l][b][f][m] f32.
__device__ __forceinline__ void fg_gather(const void* fp, const u16* pwB, int fl,
                                          size_t abase, int step, int sq,
                                          u16* a, uint4* bq) {
    const int kb = step * 64 + sq * 32;
    if (fl) {
        const float* src = (const float*)fp + abase + (size_t)kb * 1024;
        #pragma unroll
        for (int s = 0; s < 32; ++s) a[s] = f2b(src[(size_t)s * 1024]);
    } else {
        const u16* src = (const u16*)fp + abase + (size_t)kb * 1024;
        #pragma unroll
        for (int s = 0; s < 32; ++s) a[s] = src[(size_t)s * 1024];
    }
    const u16* pB = pwB + kb;
    #pragma unroll
    for (int s = 0; s < 4; ++s) bq[s] = *(const uint4*)(pB + (s << 3));
}

__global__ __launch_bounds__(256) void k_fgemm(
    const void* __restrict__ f1, const void* __restrict__ f2,
    const void* __restrict__ f3, const void* __restrict__ f4,
    const u16* __restrict__ pwT, const void* __restrict__ lwp,
    const int* __restrict__ flag, float* __restrict__ gbuf)
{
    __shared__ u16 As[128][72];
    __shared__ u16 Bs[128][72];
    const int fl = *flag;
    const int t    = threadIdx.x;
    const int lane = t & 63;
    const int wv   = t >> 6;
    const int mbase = (wv & 1) << 6;
    const int nbase = (wv >> 1) << 6;
    const int quad  = lane >> 4;
    const int l15   = lane & 15;

    const int f0 = blockIdx.x << 7;
    const int m0 = blockIdx.y << 7;
    const int b  = blockIdx.z >> 2;
    const int l  = blockIdx.z & 3;
    const void* fp = (l == 0) ? f1 : (l == 1) ? f2 : (l == 2) ? f3 : f4;

    float w0 = ldx(lwp, 0, fl), w1 = ldx(lwp, 1, fl);
    float w2 = ldx(lwp, 2, fl), w3 = ldx(lwp, 3, fl);
    float mx = fmaxf(fmaxf(w0, w1), fmaxf(w2, w3));
    float e0 = expf(w0 - mx), e1 = expf(w1 - mx), e2 = expf(w2 - mx), e3 = expf(w3 - mx);
    float es = e0 + e1 + e2 + e3;
    float lwl = ((l == 0) ? e0 : (l == 1) ? e1 : (l == 2) ? e2 : e3) / es;

    const int spx = t & 127;
    const int sq  = t >> 7;
    const size_t abase = (size_t)b * 768 * 1024 + m0 + spx;
    const u16* pwB = pwT + (size_t)l * 196608 + (size_t)(f0 + spx) * 768;

    f32x4 acc[4][4];
    #pragma unroll
    for (int i = 0; i < 4; ++i)
        #pragma unroll
        for (int j = 0; j < 4; ++j) acc[i][j] = (f32x4)0.f;

    alignas(16) u16 aA[32], aB[32];
    uint4 bA[4], bB[4];
    fg_gather(fp, pwB, fl, abase, 0, sq, aA, bA);
    for (int s = 0; s < 12; s += 2) {
        __syncthreads();
        st_stage(As, Bs, spx, sq, aA, bA);
        __syncthreads();
        fg_gather(fp, pwB, fl, abase, s + 1, sq, aB, bB);
        frag_mfma(As, Bs, mbase, nbase, l15, quad, acc);
        __syncthreads();
        st_stage(As, Bs, spx, sq, aB, bB);
        __syncthreads();
        if (s + 2 < 12) fg_gather(fp, pwB, fl, abase, s + 2, sq, aA, bA);
        frag_mfma(As, Bs, mbase, nbase, l15, quad, acc);
    }

    #pragma unroll
    for (int j = 0; j < 4; ++j) {
        const int n = f0 + nbase + (j << 4) + l15;
        float* op = gbuf + ((size_t)((l << 2) + b) * 256 + n) * 1024
                  + m0 + mbase + (quad << 2);
        #pragma unroll
        for (int i = 0; i < 4; ++i) {
            f32x4 a = acc[i][j];
            float4 o;
            o.x = lwl * 0.5f * a[0] * (1.f + erff(a[0] * 0.70710678118654752f));
            o.y = lwl * 0.5f * a[1] * (1.f + erff(a[1] * 0.70710678118654752f));
            o.z = lwl * 0.5f * a[2] * (1.f + erff(a[2] * 0.70710678118654752f));
            o.w = lwl * 0.5f * a[3] * (1.f + erff(a[3] * 0.70710678118654752f));
            *(float4*)(op + (i << 4)) = o;
        }
    }
}

// Fusion pass 2: x0 = sum over 4 layer slabs.
__global__ __launch_bounds__(256) void k_fsum(const float* __restrict__ gbuf,
                                              float* __restrict__ x0)
{
    int idx = blockIdx.x * 256 + threadIdx.x;   // 1048576 total
    x0[idx] = gbuf[idx] + gbuf[1048576 + idx]
            + gbuf[2097152 + idx] + gbuf[3145728 + idx];
}

// ---------------------------------------------------------------------------
// Depthwise 3x3 + BN + residual ReLU on (4,256,32,32) f32 -> f32
__global__ __launch_bounds__(256) void k_dw(const float* __restrict__ x0,
                                            const void* __restrict__ dww,
                                            const void* __restrict__ bnp,
                                            const int* __restrict__ flag,
                                            float* __restrict__ x1)
{
    const int fl = *flag;
    int idx = blockIdx.x * 256 + threadIdx.x;     // 1048576 total
    int n = idx & 1023;
    int f = (idx >> 10) & 255;
    int h = n >> 5, w = n & 31;
    const float* base = x0 + (idx - n);
    float acc = 0.f;
    #pragma unroll
    for (int kh = 0; kh < 3; ++kh) {
        int y = h + kh - 1;
        if (y < 0 || y >= 32) continue;
        #pragma unroll
        for (int kw = 0; kw < 3; ++kw) {
            int x = w + kw - 1;
            if (x < 0 || x >= 32) continue;
            acc += base[(y << 5) + x] * ldx(dww, f * 9 + kh * 3 + kw, fl);
        }
    }
    float g  = ldx(bnp, f, fl);
    float be = ldx(bnp, 256 + f, fl);
    float mn = ldx(bnp, 512 + f, fl);
    float vv = ldx(bnp, 768 + f, fl);
    float scale = g / sqrtf(vv + 1e-5f);
    float o = (acc - mn) * scale + be + x0[idx];
    x1[idx] = fmaxf(o, 0.f);
}

// ---------------------------------------------------------------------------
// 1x1 offset conv: act (B,256,HW) -> off (B,32,HW) f32.
template<bool ACT_BF16>
__global__ __launch_bounds__(256) void k_offs(const void* __restrict__ actv,
                                              const void* __restrict__ w,
                                              const void* __restrict__ bias,
                                              const int* __restrict__ flag,
                                              float* __restrict__ off,
                                              int HW)
{
    const int fl = *flag;
    int idx = blockIdx.x * 256 + threadIdx.x;     // B*32*HW total
    int pos = idx % HW;
    int oc  = (idx / HW) & 31;
    int b   = idx / (32 * HW);
    float acc = 0.f;
    if (ACT_BF16) {
        const u16* ap = (const u16*)actv + (size_t)b * 256 * HW + pos;
        for (int ic = 0; ic < 256; ++ic)
            acc = fmaf(b2f(ap[(size_t)ic * HW]), ldx(w, oc * 256 + ic, fl), acc);
    } else {
        const float* ap = (const float*)actv + (size_t)b * 256 * HW + pos;
        for (int ic = 0; ic < 256; ++ic)
            acc = fmaf(ap[(size_t)ic * HW], ldx(w, oc * 256 + ic, fl), acc);
    }
    off[idx] = acc + ldx(bias, oc, fl);
}

// ---------------------------------------------------------------------------
// DySample grid sample x2 -> out bf16 (nb,256,2H,2W). b derived from idx.
template<bool ACT_BF16>
__global__ __launch_bounds__(256) void k_sample(const void* __restrict__ actv,
                                                const float* __restrict__ off,
                                                u16* __restrict__ out,
                                                int H, int W)
{
    const int Wo = W << 1, Ho = H << 1;
    const int HW = H * W, HWo = Ho * Wo;
    int idx = blockIdx.x * 256 + threadIdx.x;
    int wo = idx % Wo;
    int ho = (idx / Wo) % Ho;
    int c  = (idx / HWo) & 255;
    int b  = idx / (256 * HWo);
    int g  = c >> 6;
    int h = ho >> 1, a = ho & 1, w = wo >> 1, bb = wo & 1;
    int och = g * 4 + a * 2 + bb;
    size_t obase = ((size_t)b * 32 + och) * HW + h * W + w;
    float offx = off[obase];
    float offy = off[obase + (size_t)16 * HW];
    float xp = (float)w + (bb ? 0.25f : -0.25f) + 0.25f * offx;
    float yp = (float)h + (a  ? 0.25f : -0.25f) + 0.25f * offy;
    xp = fminf(fmaxf(xp, 0.f), (float)(W - 1));
    yp = fminf(fmaxf(yp, 0.f), (float)(H - 1));
    float xf = floorf(xp), yf = floorf(yp);
    float wx = xp - xf, wy = yp - yf;
    int x0i = (int)xf; x0i = max(0, min(x0i, W - 1));
    int y0i = (int)yf; y0i = max(0, min(y0i, H - 1));
    int x1i = min(x0i + 1, W - 1);
    int y1i = min(y0i + 1, H - 1);
    float v00, v01, v10, v11;
    if (ACT_BF16) {
        const u16* ap = (const u16*)actv + ((size_t)b * 256 + c) * HW;
        v00 = b2f(ap[y0i * W + x0i]);
        v01 = b2f(ap[y0i * W + x1i]);
        v10 = b2f(ap[y1i * W + x0i]);
        v11 = b2f(ap[y1i * W + x1i]);
    } else {
        const float* ap = (const float*)actv + ((size_t)b * 256 + c) * HW;
        v00 = ap[y0i * W + x0i];
        v01 = ap[y0i * W + x1i];
        v10 = ap[y1i * W + x0i];
        v11 = ap[y1i * W + x1i];
    }
    float r = v00 * (1.f - wy) * (1.f - wx) + v01 * (1.f - wy) * wx
            + v10 * wy * (1.f - wx) + v11 * wy * wx;
    out[idx] = f2b(r);
}

// ---------------------------------------------------------------------------
// MFMA implicit-GEMM 3x3 conv 256->256 + BN + ReLU, bf16 in/out.
// Pipelined, BK=64 (36 stages). grid (2 oc-halves, HW/128, nb).
__device__ __forceinline__ void cm_gather(const u16* inb, const u16* wTo,
                                          int step, int sq, int gx, int gy,
                                          int H, int W, int HW, int oc0, int spx,
                                          u16* a, uint4* bq) {
    const int k3  = step >> 2;
    const int icc = step & 3;
    const int dh = k3 / 3, dw = k3 - dh * 3;
    const int ys = gy + dh - 1, xs = gx + dw - 1;
    const bool valid = (ys >= 0) && (ys < H) && (xs >= 0) && (xs < W);
    const u16* pA = inb + (size_t)(icc * 64 + sq * 32) * HW + ys * W + xs;
    if (valid) {
        #pragma unroll
        for (int s = 0; s < 32; ++s) a[s] = pA[(size_t)s * HW];
    } else {
        #pragma unroll
        for (int s = 0; s < 32; ++s) a[s] = 0;
    }
    const u16* pB = wTo + (size_t)k3 * 65536 + (size_t)(oc0 + spx) * 256
                  + icc * 64 + sq * 32;
    #pragma unroll
    for (int s = 0; s < 4; ++s) bq[s] = *(const uint4*)(pB + (s << 3));
}

__global__ __launch_bounds__(256) void k_cmfma(const u16* __restrict__ in,
                                               const u16* __restrict__ wTo,
                                               const void* __restrict__ bnp,
                                               const int* __restrict__ flag,
                                               u16* __restrict__ out,
                                               int H, int W, int logW)
{
    __shared__ u16 As[128][72];
    __shared__ u16 Bs[128][72];
    const int fl = *flag;
    const int HW = H * W;
    const int t    = threadIdx.x;
    const int lane = t & 63;
    const int wv   = t >> 6;
    const int mbase = (wv & 1) << 6;
    const int nbase = (wv >> 1) << 6;
    const int quad  = lane >> 4;
    const int l15   = lane & 15;

    const int oc0 = blockIdx.x << 7;
    const int px0 = blockIdx.y << 7;
    const u16* inb  = in  + (size_t)blockIdx.z * 256 * HW;
    u16*       outb = out + (size_t)blockIdx.z * 256 * HW;

    const int spx = t & 127;
    const int sq  = t >> 7;
    const int gx = (px0 + spx) & (W - 1);
    const int gy = (px0 + spx) >> logW;

    f32x4 acc[4][4];
    #pragma unroll
    for (int i = 0; i < 4; ++i)
        #pragma unroll
        for (int j = 0; j < 4; ++j) acc[i][j] = (f32x4)0.f;

    alignas(16) u16 aA[32], aB[32];
    uint4 bA[4], bB[4];
    cm_gather(inb, wTo, 0, sq, gx, gy, H, W, HW, oc0, spx, aA, bA);
    for (int s = 0; s < 36; s += 2) {
        __syncthreads();
        st_stage(As, Bs, spx, sq, aA, bA);
        __syncthreads();
        cm_gather(inb, wTo, s + 1, sq, gx, gy, H, W, HW, oc0, spx, aB, bB);
        frag_mfma(As, Bs, mbase, nbase, l15, quad, acc);
        __syncthreads();
        st_stage(As, Bs, spx, sq, aB, bB);
        __syncthreads();
        if (s + 2 < 36)
            cm_gather(inb, wTo, s + 2, sq, gx, gy, H, W, HW, oc0, spx, aA, bA);
        frag_mfma(As, Bs, mbase, nbase, l15, quad, acc);
    }

    #pragma unroll
    for (int j = 0; j < 4; ++j) {
        const int n = oc0 + nbase + (j << 4) + l15;
        float g  = ldx(bnp, n, fl);
        float be = ldx(bnp, 256 + n, fl);
        float mn = ldx(bnp, 512 + n, fl);
        float vv = ldx(bnp, 768 + n, fl);
        float scale = g / sqrtf(vv + 1e-5f);
        u16* op = outb + (size_t)n * HW + px0 + mbase + (quad << 2);
        #pragma unroll
        for (int i = 0; i < 4; ++i) {
            f32x4 a = acc[i][j];
            ushort4 o;
            o.x = f2b(fmaxf((a[0] - mn) * scale + be, 0.f));
            o.y = f2b(fmaxf((a[1] - mn) * scale + be, 0.f));
            o.z = f2b(fmaxf((a[2] - mn) * scale + be, 0.f));
            o.w = f2b(fmaxf((a[3] - mn) * scale + be, 0.f));
            *(ushort4*)(op + (i << 4)) = o;
        }
    }
}

// ---------------------------------------------------------------------------
// Head, stage A: partial 3x3 conv 256->1 over a 16-channel chunk, batched via z.
__global__ __launch_bounds__(256) void k_headp(const u16* __restrict__ in,
                                               const void* __restrict__ w,
                                               const int* __restrict__ flag,
                                               float* __restrict__ part)
{
    const int fl = *flag;
    const int icc = blockIdx.x;          // 0..15
    const int px  = blockIdx.y * 256 + threadIdx.x;   // 0..16383
    in   += (size_t)blockIdx.z * 256 * 16384;
    part += (size_t)blockIdx.z * 16 * 16384;
    const int x = px & 127, y = px >> 7;
    float acc = 0.f;
    #pragma unroll 4
    for (int i = 0; i < 16; ++i) {
        const int ic = (icc << 4) + i;
        const u16* p = in + (size_t)ic * 16384;
        float wr[9];
        #pragma unroll
        for (int k = 0; k < 9; ++k) wr[k] = ldx(w, ic * 9 + k, fl);
        #pragma unroll
        for (int kh = 0; kh < 3; ++kh) {
            int yy = y + kh - 1;
            if (yy < 0 || yy >= 128) continue;
            const u16* row = p + yy * 128;
            #pragma unroll
            for (int kw = 0; kw < 3; ++kw) {
                int xx = x + kw - 1;
                if (xx < 0 || xx >= 128) continue;
                acc = fmaf(b2f(row[xx]), wr[kh * 3 + kw], acc);
            }
        }
    }
    part[icc * 16384 + px] = acc;
}

// Head, stage B: reduce 16 partials + bias -> output (dtype per flag), batched.
__global__ __launch_bounds__(256) void k_headf(const float* __restrict__ part,
                                               const void* __restrict__ bias,
                                               const int* __restrict__ flag,
                                               void* __restrict__ outp,
                                               int b0)
{
    const int fl = *flag;
    int px = blockIdx.x * 256 + threadIdx.x;   // 16384 per batch
    part += (size_t)blockIdx.y * 16 * 16384;
    int out_ofs = (b0 + blockIdx.y) * 16384;
    float acc = ldx(bias, 0, fl);
    #pragma unroll
    for (int i = 0; i < 16; ++i) acc += part[i * 16384 + px];
    if (fl) ((float*)outp)[out_ofs + px] = acc;
    else    ((u16*)outp)[out_ofs + px] = f2b(acc);
}

// ---------------------------------------------------------------------------
extern "C" void kernel_launch(void* const* d_in, const int* in_sizes, int n_in,
                              void* d_out, int out_size, void* d_ws, size_t ws_size,
                              hipStream_t stream) {
    (void)in_sizes; (void)n_in; (void)out_size;
    const void* f1     = d_in[0];
    const void* f2     = d_in[1];
    const void* f3     = d_in[2];
    const void* f4     = d_in[3];
    const void* proj_w = d_in[4];
    const void* lwp    = d_in[5];
    const void* dw_w   = d_in[6];
    const void* bn_enh = d_in[7];
    const void* ow1    = d_in[8];
    const void* ob1    = d_in[9];
    const void* cw1    = d_in[10];
    const void* bn1    = d_in[11];
    const void* ow2    = d_in[12];
    const void* ob2    = d_in[13];
    const void* cw2    = d_in[14];
    const void* bn2    = d_in[15];
    const void* out_w  = d_in[16];
    const void* out_b  = d_in[17];

    // stage-2 chunking by available workspace (ws_size is host-visible)
    const int nb = (ws_size >= 81592320ull) ? 4
                 : (ws_size >= 48037888ull) ? 2 : 1;

    // ---- workspace layout (peak 14483456 + nb*16777216; nb=1 -> 31.26 MB) ----
    char* ws = (char*)d_ws;
    int*   flag = (int*)  (ws + 0);
    u16*   wT1  = (u16*)  (ws + 65536);
    u16*   wT2  = (u16*)  (ws + 1245184);
    u16*   pwT  = (u16*)  (ws + 2424832);
    u16*   c1   = (u16*)  (ws + 3997696);     // 8 MB bf16 (4,256,64,64)
    float* o2   = (float*)(ws + 12386304);    // 2 MB f32 (4,32,64,64)
    u16*   up2c = (u16*)  (ws + 14483456);    // nb*8 MB bf16
    u16*   c2c  = (u16*)  (ws + 14483456 + (size_t)nb * 8388608);  // nb*8 MB bf16
    float* part = (float*)(ws + 14483456);    // nb*1 MB, reuses up2c (dead post-conv2)
    float* gbuf = (float*)(ws + 3997696);     // 16 MB, dead before c1/o2/up1 written
    float* x0   = (float*)(ws + 20774912);    // 4 MB (dead before up2c/c2c written)
    float* x1   = (float*)(ws + 24969216);    // 4 MB
    float* o1   = (float*)(ws + 29163520);    // 0.5 MB
    u16*   up1  = (u16*)  (ws + 12386304);    // 8 MB, overlaps o2+up2c start (dead then)

    // 0) dtype detect
    k_detect<<<1, 256, 0, stream>>>(f1, flag);

    // weight transposes
    k_wt<<<2304, 256, 0, stream>>>(cw1, wT1, flag);
    k_wt<<<2304, 256, 0, stream>>>(cw2, wT2, flag);
    k_pwt<<<3072, 256, 0, stream>>>(proj_w, pwT, flag);

    // 1) weighted fusion (pipelined MFMA) -> gbuf, then sum -> x0
    k_fgemm<<<dim3(2, 8, 16), 256, 0, stream>>>(f1, f2, f3, f4, pwT, lwp, flag, gbuf);
    k_fsum<<<4096, 256, 0, stream>>>(gbuf, x0);

    // 2) spatial detail enhancer -> x1 f32
    k_dw<<<4096, 256, 0, stream>>>(x0, dw_w, bn_enh, flag, x1);

    // 3) dysample #1 (32->64) + conv1 -> c1 bf16 (all 4 batches)
    k_offs<false><<<512, 256, 0, stream>>>(x1, ow1, ob1, flag, o1, 32 * 32);
    k_sample<false><<<16384, 256, 0, stream>>>(x1, o1, up1, 32, 32);
    k_cmfma<<<dim3(2, 32, 4), 256, 0, stream>>>(up1, wT1, bn1, flag, c1, 64, 64, 6);

    // 4) offsets for stage 2 (all batches)
    k_offs<true><<<2048, 256, 0, stream>>>(c1, ow2, ob2, flag, o2, 64 * 64);

    // 5) chunked: dysample #2 (64->128) + conv2 + head
    for (int b0 = 0; b0 < 4; b0 += nb) {
        const u16*   c1b = c1 + (size_t)b0 * 256 * 4096;
        const float* o2b = o2 + (size_t)b0 * 32 * 4096;
        k_sample<true><<<16384 * nb, 256, 0, stream>>>(c1b, o2b, up2c, 64, 64);
        k_cmfma<<<dim3(2, 128, nb), 256, 0, stream>>>(up2c, wT2, bn2, flag, c2c,
                                                      128, 128, 7);
        k_headp<<<dim3(16, 64, nb), 256, 0, stream>>>(c2c, out_w, flag, part);
        k_headf<<<dim3(64, nb), 256, 0, stream>>>(part, out_b, flag, d_out, b0);
    }
}

// Round 9
// 645.377 us; speedup vs baseline: 1.3158x; 1.3158x over previous
//
#include <hip/hip_runtime.h>
#include <math.h>

using u16 = unsigned short;
typedef __attribute__((ext_vector_type(8))) short short8;
typedef __attribute__((ext_vector_type(4))) float f32x4;

__device__ __forceinline__ float b2f(u16 u) {
    union { unsigned int i; float f; } v; v.i = ((unsigned int)u) << 16; return v.f;
}
__device__ __forceinline__ u16 f2b(float f) {
    union { float f; unsigned int i; } v; v.f = f;
    unsigned int x = v.i;
    return (u16)((x + 0x7FFFu + ((x >> 16) & 1u)) >> 16);
}
// dtype-adaptive external load: fl=1 -> f32, fl=0 -> bf16
__device__ __forceinline__ float ldx(const void* p, long long i, int fl) {
    return fl ? ((const float*)p)[i] : b2f(((const u16*)p)[i]);
}

// ---------------------------------------------------------------------------
// Detect input dtype: read first 4096 u16 of f1 as bf16. flag=1 means f32.
__global__ __launch_bounds__(256) void k_detect(const void* p, int* flag) {
    __shared__ float m[256];
    int t = threadIdx.x;
    const u16* q = (const u16*)p;
    float lm = 0.f;
    for (int j = 0; j < 16; ++j) {
        float v = b2f(q[t * 16 + j]);
        float a = fabsf(v);
        if (!(a <= 1e30f)) a = 1e31f;   // NaN/Inf -> huge
        lm = fmaxf(lm, a);
    }
    m[t] = lm;
    __syncthreads();
    if (t == 0) {
        float mm = 0.f;
        for (int i = 0; i < 256; ++i) mm = fmaxf(mm, m[i]);
        *flag = (mm > 1000.f) ? 1 : 0;
    }
}

// ---------------------------------------------------------------------------
// Weight transpose: conv w (OC=256, IC=256, 3, 3) -> wTo[9][OC][IC] bf16
__global__ __launch_bounds__(256) void k_wt(const void* __restrict__ w,
                                            u16* __restrict__ wTo,
                                            const int* __restrict__ flag) {
    int fl = *flag;
    int idx = blockIdx.x * 256 + threadIdx.x;
    int k  = idx >> 16;          // 0..8
    int oc = (idx >> 8) & 255;
    int ic = idx & 255;
    long long s = (oc * 256 + ic) * 9 + k;
    wTo[idx] = fl ? f2b(((const float*)w)[s]) : ((const u16*)w)[s];
}

// ---------------------------------------------------------------------------
// proj_w transpose: (L=4, C=768, F=256) -> pwT[l][f][c] bf16
__global__ __launch_bounds__(256) void k_pwt(const void* __restrict__ w,
                                             u16* __restrict__ pwT,
                                             const int* __restrict__ flag) {
    int fl = *flag;
    int idx = blockIdx.x * 256 + threadIdx.x;   // 786432 total
    int c = idx % 768;
    int f = (idx / 768) & 255;
    int l = idx / (768 * 256);
    long long s = ((long long)l * 768 + c) * 256 + f;
    pwT[idx] = fl ? f2b(((const float*)w)[s]) : ((const u16*)w)[s];
}

// ---------------------------------------------------------------------------
// Fusion pass 1 (MFMA, BK=32): per (b,l) 128px x 128f GEMM over K=768,
// epilogue gelu * softmax(lw)[l] -> gbuf[l][b][f][m] f32.
__global__ __launch_bounds__(256) void k_fgemm(
    const void* __restrict__ f1, const void* __restrict__ f2,
    const void* __restrict__ f3, const void* __restrict__ f4,
    const u16* __restrict__ pwT, const void* __restrict__ lwp,
    const int* __restrict__ flag, float* __restrict__ gbuf)
{
    __shared__ u16 As[128][40];   // [px][k%32], row stride 80 B
    __shared__ u16 Bs[128][40];   // [f][k%32]
    const int fl = *flag;
    const int t    = threadIdx.x;
    const int lane = t & 63;
    const int wv   = t >> 6;
    const int mbase = (wv & 1) << 6;
    const int nbase = (wv >> 1) << 6;
    const int quad  = lane >> 4;
    const int l15   = lane & 15;

    const int f0 = blockIdx.x << 7;
    const int m0 = blockIdx.y << 7;
    const int b  = blockIdx.z >> 2;
    const int l  = blockIdx.z & 3;
    const void* fp = (l == 0) ? f1 : (l == 1) ? f2 : (l == 2) ? f3 : f4;

    float w0 = ldx(lwp, 0, fl), w1 = ldx(lwp, 1, fl);
    float w2 = ldx(lwp, 2, fl), w3 = ldx(lwp, 3, fl);
    float mx = fmaxf(fmaxf(w0, w1), fmaxf(w2, w3));
    float e0 = expf(w0 - mx), e1 = expf(w1 - mx), e2 = expf(w2 - mx), e3 = expf(w3 - mx);
    float es = e0 + e1 + e2 + e3;
    float lwl = ((l == 0) ? e0 : (l == 1) ? e1 : (l == 2) ? e2 : e3) / es;

    const int spx = t & 127;      // px (A) / f (B)
    const int sq  = t >> 7;       // which 16-k half

    f32x4 acc[4][4];
    #pragma unroll
    for (int i = 0; i < 4; ++i)
        #pragma unroll
        for (int j = 0; j < 4; ++j) acc[i][j] = (f32x4)0.f;

    const size_t abase = (size_t)b * 768 * 1024 + m0 + spx;
    const u16* srcB = pwT + (size_t)l * 196608 + (size_t)(f0 + spx) * 768 + sq * 16;

    for (int k0 = 0; k0 < 768; k0 += 32) {
        alignas(16) u16 av[16];
        if (fl) {
            #pragma unroll
            for (int s = 0; s < 16; ++s)
                av[s] = f2b(((const float*)fp)[abase + (size_t)(k0 + sq * 16 + s) * 1024]);
        } else {
            #pragma unroll
            for (int s = 0; s < 16; ++s)
                av[s] = ((const u16*)fp)[abase + (size_t)(k0 + sq * 16 + s) * 1024];
        }
        uint4 bq0 = *(const uint4*)(srcB + k0);
        uint4 bq1 = *(const uint4*)(srcB + k0 + 8);
        __syncthreads();
        *(uint4*)&As[spx][sq * 16]     = *(const uint4*)&av[0];
        *(uint4*)&As[spx][sq * 16 + 8] = *(const uint4*)&av[8];
        *(uint4*)&Bs[spx][sq * 16]     = bq0;
        *(uint4*)&Bs[spx][sq * 16 + 8] = bq1;
        __syncthreads();

        short8 af[4], bf[4];
        #pragma unroll
        for (int i = 0; i < 4; ++i)
            af[i] = *(const short8*)&As[mbase + (i << 4) + l15][quad << 3];
        #pragma unroll
        for (int j = 0; j < 4; ++j)
            bf[j] = *(const short8*)&Bs[nbase + (j << 4) + l15][quad << 3];
        #pragma unroll
        for (int i = 0; i < 4; ++i)
            #pragma unroll
            for (int j = 0; j < 4; ++j)
                acc[i][j] = __builtin_amdgcn_mfma_f32_16x16x32_bf16(
                    af[i], bf[j], acc[i][j], 0, 0, 0);
    }

    // epilogue: gelu * lw[l], f32 store
    #pragma unroll
    for (int j = 0; j < 4; ++j) {
        const int n = f0 + nbase + (j << 4) + l15;
        float* op = gbuf + ((size_t)((l << 2) + b) * 256 + n) * 1024
                  + m0 + mbase + (quad << 2);
        #pragma unroll
        for (int i = 0; i < 4; ++i) {
            f32x4 a = acc[i][j];
            float4 o;
            o.x = lwl * 0.5f * a[0] * (1.f + erff(a[0] * 0.70710678118654752f));
            o.y = lwl * 0.5f * a[1] * (1.f + erff(a[1] * 0.70710678118654752f));
            o.z = lwl * 0.5f * a[2] * (1.f + erff(a[2] * 0.70710678118654752f));
            o.w = lwl * 0.5f * a[3] * (1.f + erff(a[3] * 0.70710678118654752f));
            *(float4*)(op + (i << 4)) = o;
        }
    }
}

// Fusion pass 2: x0 = sum over 4 layer slabs.
__global__ __launch_bounds__(256) void k_fsum(const float* __restrict__ gbuf,
                                              float* __restrict__ x0)
{
    int idx = blockIdx.x * 256 + threadIdx.x;   // 1048576 total
    x0[idx] = gbuf[idx] + gbuf[1048576 + idx]
            + gbuf[2097152 + idx] + gbuf[3145728 + idx];
}

// ---------------------------------------------------------------------------
// Depthwise 3x3 + BN + residual ReLU on (4,256,32,32) f32 -> f32
__global__ __launch_bounds__(256) void k_dw(const float* __restrict__ x0,
                                            const void* __restrict__ dww,
                                            const void* __restrict__ bnp,
                                            const int* __restrict__ flag,
                                            float* __restrict__ x1)
{
    const int fl = *flag;
    int idx = blockIdx.x * 256 + threadIdx.x;     // 1048576 total
    int n = idx & 1023;
    int f = (idx >> 10) & 255;
    int h = n >> 5, w = n & 31;
    const float* base = x0 + (idx - n);
    float acc = 0.f;
    #pragma unroll
    for (int kh = 0; kh < 3; ++kh) {
        int y = h + kh - 1;
        if (y < 0 || y >= 32) continue;
        #pragma unroll
        for (int kw = 0; kw < 3; ++kw) {
            int x = w + kw - 1;
            if (x < 0 || x >= 32) continue;
            acc += base[(y << 5) + x] * ldx(dww, f * 9 + kh * 3 + kw, fl);
        }
    }
    float g  = ldx(bnp, f, fl);
    float be = ldx(bnp, 256 + f, fl);
    float mn = ldx(bnp, 512 + f, fl);
    float vv = ldx(bnp, 768 + f, fl);
    float scale = g / sqrtf(vv + 1e-5f);
    float o = (acc - mn) * scale + be + x0[idx];
    x1[idx] = fmaxf(o, 0.f);
}

// ---------------------------------------------------------------------------
// 1x1 offset conv: act (B,256,HW) -> off (B,32,HW) f32.
template<bool ACT_BF16>
__global__ __launch_bounds__(256) void k_offs(const void* __restrict__ actv,
                                              const void* __restrict__ w,
                                              const void* __restrict__ bias,
                                              const int* __restrict__ flag,
                                              float* __restrict__ off,
                                              int HW)
{
    const int fl = *flag;
    int idx = blockIdx.x * 256 + threadIdx.x;     // B*32*HW total
    int pos = idx % HW;
    int oc  = (idx / HW) & 31;
    int b   = idx / (32 * HW);
    float acc = 0.f;
    if (ACT_BF16) {
        const u16* ap = (const u16*)actv + (size_t)b * 256 * HW + pos;
        for (int ic = 0; ic < 256; ++ic)
            acc = fmaf(b2f(ap[(size_t)ic * HW]), ldx(w, oc * 256 + ic, fl), acc);
    } else {
        const float* ap = (const float*)actv + (size_t)b * 256 * HW + pos;
        for (int ic = 0; ic < 256; ++ic)
            acc = fmaf(ap[(size_t)ic * HW], ldx(w, oc * 256 + ic, fl), acc);
    }
    off[idx] = acc + ldx(bias, oc, fl);
}

// ---------------------------------------------------------------------------
// DySample grid sample x2 -> out bf16 (nb,256,2H,2W). b derived from idx.
template<bool ACT_BF16>
__global__ __launch_bounds__(256) void k_sample(const void* __restrict__ actv,
                                                const float* __restrict__ off,
                                                u16* __restrict__ out,
                                                int H, int W)
{
    const int Wo = W << 1, Ho = H << 1;
    const int HW = H * W, HWo = Ho * Wo;
    int idx = blockIdx.x * 256 + threadIdx.x;
    int wo = idx % Wo;
    int ho = (idx / Wo) % Ho;
    int c  = (idx / HWo) & 255;
    int b  = idx / (256 * HWo);
    int g  = c >> 6;
    int h = ho >> 1, a = ho & 1, w = wo >> 1, bb = wo & 1;
    int och = g * 4 + a * 2 + bb;
    size_t obase = ((size_t)b * 32 + och) * HW + h * W + w;
    float offx = off[obase];
    float offy = off[obase + (size_t)16 * HW];
    float xp = (float)w + (bb ? 0.25f : -0.25f) + 0.25f * offx;
    float yp = (float)h + (a  ? 0.25f : -0.25f) + 0.25f * offy;
    xp = fminf(fmaxf(xp, 0.f), (float)(W - 1));
    yp = fminf(fmaxf(yp, 0.f), (float)(H - 1));
    float xf = floorf(xp), yf = floorf(yp);
    float wx = xp - xf, wy = yp - yf;
    int x0i = (int)xf; x0i = max(0, min(x0i, W - 1));
    int y0i = (int)yf; y0i = max(0, min(y0i, H - 1));
    int x1i = min(x0i + 1, W - 1);
    int y1i = min(y0i + 1, H - 1);
    float v00, v01, v10, v11;
    if (ACT_BF16) {
        const u16* ap = (const u16*)actv + ((size_t)b * 256 + c) * HW;
        v00 = b2f(ap[y0i * W + x0i]);
        v01 = b2f(ap[y0i * W + x1i]);
        v10 = b2f(ap[y1i * W + x0i]);
        v11 = b2f(ap[y1i * W + x1i]);
    } else {
        const float* ap = (const float*)actv + ((size_t)b * 256 + c) * HW;
        v00 = ap[y0i * W + x0i];
        v01 = ap[y0i * W + x1i];
        v10 = ap[y1i * W + x0i];
        v11 = ap[y1i * W + x1i];
    }
    float r = v00 * (1.f - wy) * (1.f - wx) + v01 * (1.f - wy) * wx
            + v10 * wy * (1.f - wx) + v11 * wy * wx;
    out[idx] = f2b(r);
}

// ---------------------------------------------------------------------------
// MFMA implicit-GEMM 3x3 conv 256->256 + BN + ReLU, bf16 in/out. BK=32.
// grid: (2 oc-halves, HW/128 px-tiles, nb batches).
__global__ __launch_bounds__(256) void k_cmfma(const u16* __restrict__ in,
                                               const u16* __restrict__ wTo,
                                               const void* __restrict__ bnp,
                                               const int* __restrict__ flag,
                                               u16* __restrict__ out,
                                               int H, int W, int logW)
{
    __shared__ u16 As[128][40];   // [px][ic%32], row stride 80 B
    __shared__ u16 Bs[128][40];   // [oc][ic%32]
    const int fl = *flag;
    const int HW = H * W;
    const int t    = threadIdx.x;
    const int lane = t & 63;
    const int wv   = t >> 6;
    const int mbase = (wv & 1) << 6;
    const int nbase = (wv >> 1) << 6;
    const int quad  = lane >> 4;
    const int l15   = lane & 15;

    const int oc0 = blockIdx.x << 7;
    const int px0 = blockIdx.y << 7;
    const u16* inb  = in  + (size_t)blockIdx.z * 256 * HW;
    u16*       outb = out + (size_t)blockIdx.z * 256 * HW;

    const int spx = t & 127;
    const int sq  = t >> 7;
    const int gx = (px0 + spx) & (W - 1);
    const int gy = (px0 + spx) >> logW;

    f32x4 acc[4][4];
    #pragma unroll
    for (int i = 0; i < 4; ++i)
        #pragma unroll
        for (int j = 0; j < 4; ++j) acc[i][j] = (f32x4)0.f;

    for (int k3 = 0; k3 < 9; ++k3) {
        const int dh = k3 / 3, dw = k3 % 3;
        const int ys = gy + dh - 1;
        const int xs = gx + dw - 1;
        const bool valid = (ys >= 0) && (ys < H) && (xs >= 0) && (xs < W);
        const u16* srcA = inb + (size_t)(sq * 16) * HW + ys * W + xs;
        const u16* srcB = wTo + (size_t)k3 * 65536 + (size_t)(oc0 + spx) * 256 + sq * 16;

        for (int ic0 = 0; ic0 < 256; ic0 += 32) {
            alignas(16) u16 av[16];
            if (valid) {
                #pragma unroll
                for (int s = 0; s < 16; ++s)
                    av[s] = srcA[(size_t)(ic0 + s) * HW];
            } else {
                #pragma unroll
                for (int s = 0; s < 16; ++s) av[s] = 0;
            }
            uint4 bq0 = *(const uint4*)(srcB + ic0);
            uint4 bq1 = *(const uint4*)(srcB + ic0 + 8);
            __syncthreads();
            *(uint4*)&As[spx][sq * 16]     = *(const uint4*)&av[0];
            *(uint4*)&As[spx][sq * 16 + 8] = *(const uint4*)&av[8];
            *(uint4*)&Bs[spx][sq * 16]     = bq0;
            *(uint4*)&Bs[spx][sq * 16 + 8] = bq1;
            __syncthreads();

            short8 af[4], bf[4];
            #pragma unroll
            for (int i = 0; i < 4; ++i)
                af[i] = *(const short8*)&As[mbase + (i << 4) + l15][quad << 3];
            #pragma unroll
            for (int j = 0; j < 4; ++j)
                bf[j] = *(const short8*)&Bs[nbase + (j << 4) + l15][quad << 3];
            #pragma unroll
            for (int i = 0; i < 4; ++i)
                #pragma unroll
                for (int j = 0; j < 4; ++j)
                    acc[i][j] = __builtin_amdgcn_mfma_f32_16x16x32_bf16(
                        af[i], bf[j], acc[i][j], 0, 0, 0);
        }
    }

    #pragma unroll
    for (int j = 0; j < 4; ++j) {
        const int n = oc0 + nbase + (j << 4) + l15;
        float g  = ldx(bnp, n, fl);
        float be = ldx(bnp, 256 + n, fl);
        float mn = ldx(bnp, 512 + n, fl);
        float vv = ldx(bnp, 768 + n, fl);
        float scale = g / sqrtf(vv + 1e-5f);
        u16* op = outb + (size_t)n * HW + px0 + mbase + (quad << 2);
        #pragma unroll
        for (int i = 0; i < 4; ++i) {
            f32x4 a = acc[i][j];
            ushort4 o;
            o.x = f2b(fmaxf((a[0] - mn) * scale + be, 0.f));
            o.y = f2b(fmaxf((a[1] - mn) * scale + be, 0.f));
            o.z = f2b(fmaxf((a[2] - mn) * scale + be, 0.f));
            o.w = f2b(fmaxf((a[3] - mn) * scale + be, 0.f));
            *(ushort4*)(op + (i << 4)) = o;
        }
    }
}

// ---------------------------------------------------------------------------
// Head, stage A: partial 3x3 conv 256->1 over a 16-channel chunk, batched via z.
__global__ __launch_bounds__(256) void k_headp(const u16* __restrict__ in,
                                               const void* __restrict__ w,
                                               const int* __restrict__ flag,
                                               float* __restrict__ part)
{
    const int fl = *flag;
    const int icc = blockIdx.x;          // 0..15
    const int px  = blockIdx.y * 256 + threadIdx.x;   // 0..16383
    in   += (size_t)blockIdx.z * 256 * 16384;
    part += (size_t)blockIdx.z * 16 * 16384;
    const int x = px & 127, y = px >> 7;
    float acc = 0.f;
    #pragma unroll 4
    for (int i = 0; i < 16; ++i) {
        const int ic = (icc << 4) + i;
        const u16* p = in + (size_t)ic * 16384;
        float wr[9];
        #pragma unroll
        for (int k = 0; k < 9; ++k) wr[k] = ldx(w, ic * 9 + k, fl);
        #pragma unroll
        for (int kh = 0; kh < 3; ++kh) {
            int yy = y + kh - 1;
            if (yy < 0 || yy >= 128) continue;
            const u16* row = p + yy * 128;
            #pragma unroll
            for (int kw = 0; kw < 3; ++kw) {
                int xx = x + kw - 1;
                if (xx < 0 || xx >= 128) continue;
                acc = fmaf(b2f(row[xx]), wr[kh * 3 + kw], acc);
            }
        }
    }
    part[icc * 16384 + px] = acc;
}

// Head, stage B: reduce 16 partials + bias -> output (dtype per flag), batched.
__global__ __launch_bounds__(256) void k_headf(const float* __restrict__ part,
                                               const void* __restrict__ bias,
                                               const int* __restrict__ flag,
                                               void* __restrict__ outp,
                                               int b0)
{
    const int fl = *flag;
    int px = blockIdx.x * 256 + threadIdx.x;   // 16384 per batch
    part += (size_t)blockIdx.y * 16 * 16384;
    int out_ofs = (b0 + blockIdx.y) * 16384;
    float acc = ldx(bias, 0, fl);
    #pragma unroll
    for (int i = 0; i < 16; ++i) acc += part[i * 16384 + px];
    if (fl) ((float*)outp)[out_ofs + px] = acc;
    else    ((u16*)outp)[out_ofs + px] = f2b(acc);
}

// ---------------------------------------------------------------------------
extern "C" void kernel_launch(void* const* d_in, const int* in_sizes, int n_in,
                              void* d_out, int out_size, void* d_ws, size_t ws_size,
                              hipStream_t stream) {
    (void)in_sizes; (void)n_in; (void)out_size;
    const void* f1     = d_in[0];
    const void* f2     = d_in[1];
    const void* f3     = d_in[2];
    const void* f4     = d_in[3];
    const void* proj_w = d_in[4];
    const void* lwp    = d_in[5];
    const void* dw_w   = d_in[6];
    const void* bn_enh = d_in[7];
    const void* ow1    = d_in[8];
    const void* ob1    = d_in[9];
    const void* cw1    = d_in[10];
    const void* bn1    = d_in[11];
    const void* ow2    = d_in[12];
    const void* ob2    = d_in[13];
    const void* cw2    = d_in[14];
    const void* bn2    = d_in[15];
    const void* out_w  = d_in[16];
    const void* out_b  = d_in[17];

    // stage-2 chunking by available workspace (ws_size is host-visible)
    const int nb = (ws_size >= 81592320ull) ? 4
                 : (ws_size >= 48037888ull) ? 2 : 1;

    // ---- workspace layout (peak 14483456 + nb*16777216; nb=1 -> 31.26 MB) ----
    char* ws = (char*)d_ws;
    int*   flag = (int*)  (ws + 0);
    u16*   wT1  = (u16*)  (ws + 65536);
    u16*   wT2  = (u16*)  (ws + 1245184);
    u16*   pwT  = (u16*)  (ws + 2424832);
    u16*   c1   = (u16*)  (ws + 3997696);     // 8 MB bf16 (4,256,64,64)
    float* o2   = (float*)(ws + 12386304);    // 2 MB f32 (4,32,64,64)
    u16*   up2c = (u16*)  (ws + 14483456);    // nb*8 MB bf16
    u16*   c2c  = (u16*)  (ws + 14483456 + (size_t)nb * 8388608);  // nb*8 MB bf16
    float* part = (float*)(ws + 14483456);    // nb*1 MB, reuses up2c (dead post-conv2)
    float* gbuf = (float*)(ws + 3997696);     // 16 MB, dead before c1/o2/up1 written
    float* x0   = (float*)(ws + 20774912);    // 4 MB (dead before up2c/c2c written)
    float* x1   = (float*)(ws + 24969216);    // 4 MB
    float* o1   = (float*)(ws + 29163520);    // 0.5 MB
    u16*   up1  = (u16*)  (ws + 12386304);    // 8 MB, overlaps o2+up2c start (dead then)

    // 0) dtype detect
    k_detect<<<1, 256, 0, stream>>>(f1, flag);

    // weight transposes
    k_wt<<<2304, 256, 0, stream>>>(cw1, wT1, flag);
    k_wt<<<2304, 256, 0, stream>>>(cw2, wT2, flag);
    k_pwt<<<3072, 256, 0, stream>>>(proj_w, pwT, flag);

    // 1) weighted fusion (MFMA) -> gbuf, then sum -> x0
    k_fgemm<<<dim3(2, 8, 16), 256, 0, stream>>>(f1, f2, f3, f4, pwT, lwp, flag, gbuf);
    k_fsum<<<4096, 256, 0, stream>>>(gbuf, x0);

    // 2) spatial detail enhancer -> x1 f32
    k_dw<<<4096, 256, 0, stream>>>(x0, dw_w, bn_enh, flag, x1);

    // 3) dysample #1 (32->64) + conv1 -> c1 bf16 (all 4 batches)
    k_offs<false><<<512, 256, 0, stream>>>(x1, ow1, ob1, flag, o1, 32 * 32);
    k_sample<false><<<16384, 256, 0, stream>>>(x1, o1, up1, 32, 32);
    k_cmfma<<<dim3(2, 32, 4), 256, 0, stream>>>(up1, wT1, bn1, flag, c1, 64, 64, 6);

    // 4) offsets for stage 2 (all batches)
    k_offs<true><<<2048, 256, 0, stream>>>(c1, ow2, ob2, flag, o2, 64 * 64);

    // 5) chunked: dysample #2 (64->128) + conv2 + head
    for (int b0 = 0; b0 < 4; b0 += nb) {
        const u16*   c1b = c1 + (size_t)b0 * 256 * 4096;
        const float* o2b = o2 + (size_t)b0 * 32 * 4096;
        k_sample<true><<<16384 * nb, 256, 0, stream>>>(c1b, o2b, up2c, 64, 64);
        k_cmfma<<<dim3(2, 128, nb), 256, 0, stream>>>(up2c, wT2, bn2, flag, c2c,
                                                      128, 128, 7);
        k_headp<<<dim3(16, 64, nb), 256, 0, stream>>>(c2c, out_w, flag, part);
        k_headf<<<dim3(64, nb), 256, 0, stream>>>(part, out_b, flag, d_out, b0);
    }
}